// Round 1
// baseline (113.038 us; speedup 1.0000x reference)
//
#include <hip/hip_runtime.h>

// Kalman filter: T=500 sequential steps, N=16384 independent tracks.
// One thread per track; state (mean[4], symmetric covar[10]) lives in
// registers across the whole T loop. Inputs streamed with a depth-PF
// register ring prefetch (loads are independent of the serial compute
// chain, so they hide HBM latency even at 1 wave/CU).

#define TSTEPS 500
#define NTRK   16384
#define LOG2N  14          // N == 1<<14
#define PF     10          // 500 % 10 == 0 -> no tail iteration

__global__ __launch_bounds__(64, 1) void kf_kernel(
    const float* __restrict__ zl,    // (T, N, 2)
    const float* __restrict__ lh,    // (T, N, 3)
    const float* __restrict__ pos0,  // (N, 2)
    const float* __restrict__ vel0,  // (N, 2)
    const float* __restrict__ dq,    // (4,)
    float* __restrict__ yo)          // (T, N, 2)
{
    const int n = blockIdx.x * 64 + threadIdx.x;

    // Q diagonal: uniform across threads -> scalar loads
    const float q0 = dq[0], q1 = dq[1], q2 = dq[2], q3 = dq[3];

    // state mean (px, py, vx, vy)
    float m0 = pos0[2 * n + 0];
    float m1 = pos0[2 * n + 1];
    float m2 = vel0[2 * n + 0];
    float m3 = vel0[2 * n + 1];

    // symmetric covariance, init = I4
    float p00 = 1.f, p01 = 0.f, p02 = 0.f, p03 = 0.f;
    float p11 = 1.f, p12 = 0.f, p13 = 0.f;
    float p22 = 1.f, p23 = 0.f;
    float p33 = 1.f;

    // prefetch ring (all indices static via full unroll)
    float zb0[PF], zb1[PF], lb0[PF], lb1[PF], lb2[PF];
#pragma unroll
    for (int k = 0; k < PF; ++k) {
        const int idx = (k << LOG2N) + n;              // k*N + n
        const float2 zz = *reinterpret_cast<const float2*>(zl + (size_t)idx * 2);
        zb0[k] = zz.x; zb1[k] = zz.y;
        const float* lp = lh + (size_t)idx * 3;
        lb0[k] = lp[0]; lb1[k] = lp[1]; lb2[k] = lp[2];
    }

    for (int tt = 0; tt < TSTEPS; tt += PF) {
#pragma unroll
        for (int k = 0; k < PF; ++k) {
            const int t = tt + k;                      // t <= 499 always
            const float z0 = zb0[k], z1 = zb1[k];
            const float L0 = lb0[k], L1 = lb1[k], L2 = lb2[k];

            // issue prefetch for t+PF (clamped; redundant loads at the
            // tail are harmless and keep the loop tail-free)
            int tp = t + PF; tp = (tp < TSTEPS) ? tp : (TSTEPS - 1);
            {
                const int idx = (tp << LOG2N) + n;
                const float2 zz = *reinterpret_cast<const float2*>(zl + (size_t)idx * 2);
                zb0[k] = zz.x; zb1[k] = zz.y;
                const float* lp = lh + (size_t)idx * 3;
                lb0[k] = lp[0]; lb1[k] = lp[1]; lb2[k] = lp[2];
            }

            // ---- predict: P' = A P A^T + Q (A: pos += vel) ----
            const float np00 = p00 + p02 + p02 + p22 + q0;
            const float np01 = p01 + p03 + p12 + p23;
            const float np02 = p02 + p22;
            const float np03 = p03 + p23;
            const float np11 = p11 + p13 + p13 + p33 + q1;
            const float np12 = p12 + p23;
            const float np13 = p13 + p33;
            const float np22 = p22 + q2;
            const float np23 = p23;
            const float np33 = p33 + q3;

            const float m0p = m0 + m2;
            const float m1p = m1 + m3;

            // ---- measurement noise R = L L^T (L lower-tri from L_hat) ----
            const float l00 = __expf(L0);
            const float l10 = L1;
            const float l11 = __expf(L2);
            const float r00 = l00 * l00;
            const float r01 = l00 * l10;
            const float r11 = fmaf(l10, l10, l11 * l11);

            // ---- innovation covariance S = P'[0:2,0:2] + R, inverse ----
            const float s00 = np00 + r00;
            const float s01 = np01 + r01;
            const float s11 = np11 + r11;
            const float det = fmaf(s00, s11, -(s01 * s01));
            const float id  = __builtin_amdgcn_rcpf(det);
            const float i00 = s11 * id;
            const float i01 = -(s01 * id);
            const float i11 = s00 * id;

            // ---- Kalman gain K = P'[:,0:2] @ Sinv  (4x2) ----
            const float k00 = fmaf(np00, i00, np01 * i01);
            const float k01 = fmaf(np00, i01, np01 * i11);
            const float k10 = fmaf(np01, i00, np11 * i01);
            const float k11 = fmaf(np01, i01, np11 * i11);
            const float k20 = fmaf(np02, i00, np12 * i01);
            const float k21 = fmaf(np02, i01, np12 * i11);
            const float k30 = fmaf(np03, i00, np13 * i01);
            const float k31 = fmaf(np03, i01, np13 * i11);

            // ---- mean update ----
            const float e0 = z0 - m0p;
            const float e1 = z1 - m1p;
            m0 = fmaf(k01, e1, fmaf(k00, e0, m0p));
            m1 = fmaf(k11, e1, fmaf(k10, e0, m1p));
            m2 = fmaf(k21, e1, fmaf(k20, e0, m2));
            m3 = fmaf(k31, e1, fmaf(k30, e0, m3));

            // ---- covariance update (simplified): P = (I - K Cz) P' ----
            // row0 of P' = (np00,np01,np02,np03); row1 = (np01,np11,np12,np13)
            p00 = np00 - fmaf(k00, np00, k01 * np01);
            p01 = np01 - fmaf(k00, np01, k01 * np11);
            p02 = np02 - fmaf(k00, np02, k01 * np12);
            p03 = np03 - fmaf(k00, np03, k01 * np13);
            p11 = np11 - fmaf(k10, np01, k11 * np11);
            p12 = np12 - fmaf(k10, np02, k11 * np12);
            p13 = np13 - fmaf(k10, np03, k11 * np13);
            p22 = np22 - fmaf(k20, np02, k21 * np12);
            p23 = np23 - fmaf(k20, np03, k21 * np13);
            p33 = np33 - fmaf(k30, np03, k31 * np13);

            // ---- y_hat = mean_new[0:2] ----
            const int oidx = (t << LOG2N) + n;
            *reinterpret_cast<float2*>(yo + (size_t)oidx * 2) = make_float2(m0, m1);
        }
    }
}

extern "C" void kernel_launch(void* const* d_in, const int* in_sizes, int n_in,
                              void* d_out, int out_size, void* d_ws, size_t ws_size,
                              hipStream_t stream) {
    const float* zl   = (const float*)d_in[0];
    const float* lh   = (const float*)d_in[1];
    const float* pos0 = (const float*)d_in[2];
    const float* vel0 = (const float*)d_in[3];
    const float* dq   = (const float*)d_in[4];
    float* yo = (float*)d_out;

    kf_kernel<<<NTRK / 64, 64, 0, stream>>>(zl, lh, pos0, vel0, dq, yo);
}

// Round 2
// 111.668 us; speedup vs baseline: 1.0123x; 1.0123x over previous
//
#include <hip/hip_runtime.h>
#include <stdint.h>

// Kalman filter: T=500 sequential steps, N=16384 independent tracks.
// One thread per track (256 blocks x 64 = 1 wave/block, no barriers needed).
// Inputs streamed through double-buffered LDS tiles staged with
// global_load_lds dwordx4 (1 KB/instruction, perfectly coalesced); compute
// reads per-step values from LDS (short lgkm latency, hidden by the
// unrolled 20-step tile body). vmcnt waits collapse to one point per tile.

#define TSTEPS 500
#define G      20          // steps per tile; 500 = 25 tiles = 1 + 12*2
#define LOG2N  14          // N == 1<<14
#define NTRK   16384

typedef const __attribute__((address_space(1))) uint32_t glb_u32;
typedef __attribute__((address_space(3))) uint32_t lds_u32;

// Stage one G-step tile of z (G x 64 x 2 f32 = 10 KB) and L_hat
// (G x 64 x 3 f32 = 15 KB) into LDS, preserving raw global byte order
// row-by-row. Each global_load_lds moves 64 lanes x 16 B = 1024 B.
__device__ __forceinline__ void stage_tile(const char* zb, const char* lb,
                                           float* zdst, float* ldst,
                                           int t0, size_t n0z, size_t n0l,
                                           int lane16) {
#pragma unroll
    for (int i = 0; i < 10; ++i) {                 // z: 20 rows x 512 B
        const int off = i * 1024 + lane16;
        const int row = off >> 9;                  // /512
        const int col = off & 511;
        const char* g = zb + (size_t)(t0 + row) * 131072 + n0z + col;
        __builtin_amdgcn_global_load_lds((glb_u32*)g,
            (lds_u32*)((char*)zdst + i * 1024), 16, 0, 0);
    }
#pragma unroll
    for (int i = 0; i < 15; ++i) {                 // lh: 20 rows x 768 B
        const int off = i * 1024 + lane16;
        const int u   = off >> 8;                  // off/256 (< 60)
        const int row = (u * 43691) >> 17;         // exact u/3
        const int col = off - row * 768;
        const char* g = lb + (size_t)(t0 + row) * 196608 + n0l + col;
        __builtin_amdgcn_global_load_lds((glb_u32*)g,
            (lds_u32*)((char*)ldst + i * 1024), 16, 0, 0);
    }
}

__device__ __forceinline__ void do_tile(
    float& m0, float& m1, float& m2, float& m3,
    float& p00, float& p01, float& p02, float& p03,
    float& p11, float& p12, float& p13,
    float& p22, float& p23, float& p33,
    const float* zsh, const float* lsh,
    float2* yo, int t0, int tid, int n,
    float q0, float q1, float q2, float q3)
{
#pragma unroll
    for (int k = 0; k < G; ++k) {
        const float2 zz = ((const float2*)zsh)[k * 64 + tid];
        const int lbase = (k * 64 + tid) * 3;
        const float L0 = lsh[lbase + 0];
        const float L1 = lsh[lbase + 1];
        const float L2 = lsh[lbase + 2];

        // ---- predict: P' = A P A^T + Q (A: pos += vel) ----
        const float np00 = p00 + p02 + p02 + p22 + q0;
        const float np01 = p01 + p03 + p12 + p23;
        const float np02 = p02 + p22;
        const float np03 = p03 + p23;
        const float np11 = p11 + p13 + p13 + p33 + q1;
        const float np12 = p12 + p23;
        const float np13 = p13 + p33;
        const float np22 = p22 + q2;
        const float np23 = p23;
        const float np33 = p33 + q3;

        const float m0p = m0 + m2;
        const float m1p = m1 + m3;

        // ---- R = L L^T ----
        const float l00 = __expf(L0);
        const float l10 = L1;
        const float l11 = __expf(L2);
        const float r00 = l00 * l00;
        const float r01 = l00 * l10;
        const float r11 = fmaf(l10, l10, l11 * l11);

        // ---- S = P'[0:2,0:2] + R, closed-form inverse ----
        const float s00 = np00 + r00;
        const float s01 = np01 + r01;
        const float s11 = np11 + r11;
        const float det = fmaf(s00, s11, -(s01 * s01));
        const float id  = __builtin_amdgcn_rcpf(det);
        const float i00 = s11 * id;
        const float i01 = -(s01 * id);
        const float i11 = s00 * id;

        // ---- K = P'[:,0:2] @ Sinv ----
        const float k00 = fmaf(np00, i00, np01 * i01);
        const float k01 = fmaf(np00, i01, np01 * i11);
        const float k10 = fmaf(np01, i00, np11 * i01);
        const float k11 = fmaf(np01, i01, np11 * i11);
        const float k20 = fmaf(np02, i00, np12 * i01);
        const float k21 = fmaf(np02, i01, np12 * i11);
        const float k30 = fmaf(np03, i00, np13 * i01);
        const float k31 = fmaf(np03, i01, np13 * i11);

        // ---- mean update ----
        const float e0 = zz.x - m0p;
        const float e1 = zz.y - m1p;
        m0 = fmaf(k01, e1, fmaf(k00, e0, m0p));
        m1 = fmaf(k11, e1, fmaf(k10, e0, m1p));
        m2 = fmaf(k21, e1, fmaf(k20, e0, m2));
        m3 = fmaf(k31, e1, fmaf(k30, e0, m3));

        // ---- covariance update: P = (I - K Cz) P' ----
        p00 = np00 - fmaf(k00, np00, k01 * np01);
        p01 = np01 - fmaf(k00, np01, k01 * np11);
        p02 = np02 - fmaf(k00, np02, k01 * np12);
        p03 = np03 - fmaf(k00, np03, k01 * np13);
        p11 = np11 - fmaf(k10, np01, k11 * np11);
        p12 = np12 - fmaf(k10, np02, k11 * np12);
        p13 = np13 - fmaf(k10, np03, k11 * np13);
        p22 = np22 - fmaf(k20, np02, k21 * np12);
        p23 = np23 - fmaf(k20, np03, k21 * np13);
        p33 = np33 - fmaf(k30, np03, k31 * np13);

        // ---- y_hat ----
        yo[((size_t)(t0 + k) << LOG2N) + n] = make_float2(m0, m1);
    }
}

__global__ __launch_bounds__(64, 1) void kf_kernel(
    const float* __restrict__ zl,    // (T, N, 2)
    const float* __restrict__ lh,    // (T, N, 3)
    const float* __restrict__ pos0,  // (N, 2)
    const float* __restrict__ vel0,  // (N, 2)
    const float* __restrict__ dq,    // (4,)
    float* __restrict__ yo)          // (T, N, 2)
{
    __shared__ float zshA[G * 64 * 2];
    __shared__ float zshB[G * 64 * 2];
    __shared__ float lshA[G * 64 * 3];
    __shared__ float lshB[G * 64 * 3];

    const int tid = threadIdx.x;
    const int n = blockIdx.x * 64 + tid;
    const size_t n0z = (size_t)blockIdx.x * 64 * 8;   // byte offset of track block in a z row
    const size_t n0l = (size_t)blockIdx.x * 64 * 12;  // ... in an lh row
    const int lane16 = tid * 16;

    const float q0 = dq[0], q1 = dq[1], q2 = dq[2], q3 = dq[3];

    float m0 = pos0[2 * n + 0];
    float m1 = pos0[2 * n + 1];
    float m2 = vel0[2 * n + 0];
    float m3 = vel0[2 * n + 1];

    float p00 = 1.f, p01 = 0.f, p02 = 0.f, p03 = 0.f;
    float p11 = 1.f, p12 = 0.f, p13 = 0.f;
    float p22 = 1.f, p23 = 0.f;
    float p33 = 1.f;

    const char* zb = (const char*)zl;
    const char* lb = (const char*)lh;
    float2* yo2 = (float2*)yo;

#define DO_TILE(Z, L, T0) \
    do_tile(m0, m1, m2, m3, p00, p01, p02, p03, p11, p12, p13, p22, p23, p33, \
            Z, L, yo2, T0, tid, n, q0, q1, q2, q3)

    stage_tile(zb, lb, zshA, lshA, 0, n0z, n0l, lane16);

#pragma unroll 1
    for (int b = 0; b < 12; ++b) {
        const int t0 = b * 2 * G;
        stage_tile(zb, lb, zshB, lshB, t0 + G, n0z, n0l, lane16);
        DO_TILE(zshA, lshA, t0);
        stage_tile(zb, lb, zshA, lshA, t0 + 2 * G, n0z, n0l, lane16);
        DO_TILE(zshB, lshB, t0 + G);
    }
    DO_TILE(zshA, lshA, TSTEPS - G);   // tile 24, staged in the last loop iter

#undef DO_TILE
}

extern "C" void kernel_launch(void* const* d_in, const int* in_sizes, int n_in,
                              void* d_out, int out_size, void* d_ws, size_t ws_size,
                              hipStream_t stream) {
    const float* zl   = (const float*)d_in[0];
    const float* lh   = (const float*)d_in[1];
    const float* pos0 = (const float*)d_in[2];
    const float* vel0 = (const float*)d_in[3];
    const float* dq   = (const float*)d_in[4];
    float* yo = (float*)d_out;

    kf_kernel<<<NTRK / 64, 64, 0, stream>>>(zl, lh, pos0, vel0, dq, yo);
}

// Round 3
// 108.353 us; speedup vs baseline: 1.0432x; 1.0306x over previous
//
#include <hip/hip_runtime.h>

// Kalman filter: T=500 sequential steps, N=16384 independent tracks.
// One thread per track; 256 blocks x 64 threads = 1 wave/CU (structural).
// Latency-bound regime -> all input data is streamed through DOUBLE-BUFFERED
// REGISTER tiles (G=10 steps each). A tile's loads are issued one full tile
// of compute (~1600+ cycles) ahead of first use, so the single counted
// vmcnt wait at tile entry finds the data already resident (L3-hot inputs).
// Within a tile: pure register math, zero memory waits. All tile arrays are
// indexed by compile-time constants (full unroll) so they live in VGPRs.

#define TSTEPS 500
#define G      10          // steps per register tile; 500 = 50 tiles
#define LOG2N  14          // N == 1<<14
#define NTRK   16384

struct F3 { float x, y, z; };   // 12 B, align 4 -> global_load_dwordx3

struct Tile {
    float z0[G], z1[G], l0[G], l1[G], l2[G];
};

__device__ __forceinline__ void load_tile(Tile& tb,
                                          const float2* __restrict__ zl2,
                                          const F3* __restrict__ lh3,
                                          int t0, int n) {
#pragma unroll
    for (int k = 0; k < G; ++k) {
        const int idx = ((t0 + k) << LOG2N) + n;
        const float2 zz = zl2[idx];
        const F3   ll = lh3[idx];
        tb.z0[k] = zz.x; tb.z1[k] = zz.y;
        tb.l0[k] = ll.x; tb.l1[k] = ll.y; tb.l2[k] = ll.z;
    }
}

struct KFState {
    float m0, m1, m2, m3;
    float p00, p01, p02, p03, p11, p12, p13, p22, p23, p33;
};

__device__ __forceinline__ void compute_tile(const Tile& tb, KFState& s,
                                             float2* __restrict__ yo2,
                                             int t0, int n,
                                             float q0, float q1, float q2, float q3) {
#pragma unroll
    for (int k = 0; k < G; ++k) {
        const float z0 = tb.z0[k], z1 = tb.z1[k];
        const float L0 = tb.l0[k], L1 = tb.l1[k], L2 = tb.l2[k];

        // ---- predict: P' = A P A^T + Q (A: pos += vel) ----
        const float np00 = s.p00 + s.p02 + s.p02 + s.p22 + q0;
        const float np01 = s.p01 + s.p03 + s.p12 + s.p23;
        const float np02 = s.p02 + s.p22;
        const float np03 = s.p03 + s.p23;
        const float np11 = s.p11 + s.p13 + s.p13 + s.p33 + q1;
        const float np12 = s.p12 + s.p23;
        const float np13 = s.p13 + s.p33;
        const float np22 = s.p22 + q2;
        const float np23 = s.p23;
        const float np33 = s.p33 + q3;

        const float m0p = s.m0 + s.m2;
        const float m1p = s.m1 + s.m3;

        // ---- R = L L^T ----
        const float l00 = __expf(L0);
        const float l10 = L1;
        const float l11 = __expf(L2);
        const float r00 = l00 * l00;
        const float r01 = l00 * l10;
        const float r11 = fmaf(l10, l10, l11 * l11);

        // ---- S = P'[0:2,0:2] + R, closed-form 2x2 inverse ----
        const float s00 = np00 + r00;
        const float s01 = np01 + r01;
        const float s11 = np11 + r11;
        const float det = fmaf(s00, s11, -(s01 * s01));
        const float id  = __builtin_amdgcn_rcpf(det);
        const float i00 = s11 * id;
        const float i01 = -(s01 * id);
        const float i11 = s00 * id;

        // ---- K = P'[:,0:2] @ Sinv ----
        const float k00 = fmaf(np00, i00, np01 * i01);
        const float k01 = fmaf(np00, i01, np01 * i11);
        const float k10 = fmaf(np01, i00, np11 * i01);
        const float k11 = fmaf(np01, i01, np11 * i11);
        const float k20 = fmaf(np02, i00, np12 * i01);
        const float k21 = fmaf(np02, i01, np12 * i11);
        const float k30 = fmaf(np03, i00, np13 * i01);
        const float k31 = fmaf(np03, i01, np13 * i11);

        // ---- mean update ----
        const float e0 = z0 - m0p;
        const float e1 = z1 - m1p;
        s.m0 = fmaf(k01, e1, fmaf(k00, e0, m0p));
        s.m1 = fmaf(k11, e1, fmaf(k10, e0, m1p));
        s.m2 = fmaf(k21, e1, fmaf(k20, e0, s.m2));
        s.m3 = fmaf(k31, e1, fmaf(k30, e0, s.m3));

        // ---- covariance update: P = (I - K Cz) P' ----
        s.p00 = np00 - fmaf(k00, np00, k01 * np01);
        s.p01 = np01 - fmaf(k00, np01, k01 * np11);
        s.p02 = np02 - fmaf(k00, np02, k01 * np12);
        s.p03 = np03 - fmaf(k00, np03, k01 * np13);
        s.p11 = np11 - fmaf(k10, np01, k11 * np11);
        s.p12 = np12 - fmaf(k10, np02, k11 * np12);
        s.p13 = np13 - fmaf(k10, np03, k11 * np13);
        s.p22 = np22 - fmaf(k20, np02, k21 * np12);
        s.p23 = np23 - fmaf(k20, np03, k21 * np13);
        s.p33 = np33 - fmaf(k30, np03, k31 * np13);

        // ---- y_hat = mean_new[0:2] (store: fire-and-forget) ----
        yo2[((t0 + k) << LOG2N) + n] = make_float2(s.m0, s.m1);
    }
}

__global__ __launch_bounds__(64, 1) void kf_kernel(
    const float* __restrict__ zl,    // (T, N, 2)
    const float* __restrict__ lh,    // (T, N, 3)
    const float* __restrict__ pos0,  // (N, 2)
    const float* __restrict__ vel0,  // (N, 2)
    const float* __restrict__ dq,    // (4,)
    float* __restrict__ yo)          // (T, N, 2)
{
    const int n = blockIdx.x * 64 + threadIdx.x;
    const float2* zl2 = (const float2*)zl;
    const F3*     lh3 = (const F3*)lh;
    float2*       yo2 = (float2*)yo;

    const float q0 = dq[0], q1 = dq[1], q2 = dq[2], q3 = dq[3];

    KFState s;
    s.m0 = pos0[2 * n + 0];
    s.m1 = pos0[2 * n + 1];
    s.m2 = vel0[2 * n + 0];
    s.m3 = vel0[2 * n + 1];
    s.p00 = 1.f; s.p01 = 0.f; s.p02 = 0.f; s.p03 = 0.f;
    s.p11 = 1.f; s.p12 = 0.f; s.p13 = 0.f;
    s.p22 = 1.f; s.p23 = 0.f;
    s.p33 = 1.f;

    Tile A, B;
    load_tile(A, zl2, lh3, 0, n);
    load_tile(B, zl2, lh3, G, n);

    // 50 tiles total: prologue holds tiles 0,1; loop t0 = 0..460 step 20
    // computes tiles {t0, t0+G} and loads {t0+2G, t0+3G}; epilogue computes
    // the final two tiles (480, 490) already loaded by the last iteration.
#pragma unroll 1
    for (int t0 = 0; t0 < TSTEPS - 2 * G; t0 += 2 * G) {
        compute_tile(A, s, yo2, t0, n, q0, q1, q2, q3);
        load_tile(A, zl2, lh3, t0 + 2 * G, n);
        compute_tile(B, s, yo2, t0 + G, n, q0, q1, q2, q3);
        load_tile(B, zl2, lh3, t0 + 3 * G, n);
    }
    compute_tile(A, s, yo2, TSTEPS - 2 * G, n, q0, q1, q2, q3);
    compute_tile(B, s, yo2, TSTEPS - G, n, q0, q1, q2, q3);
}

extern "C" void kernel_launch(void* const* d_in, const int* in_sizes, int n_in,
                              void* d_out, int out_size, void* d_ws, size_t ws_size,
                              hipStream_t stream) {
    const float* zl   = (const float*)d_in[0];
    const float* lh   = (const float*)d_in[1];
    const float* pos0 = (const float*)d_in[2];
    const float* vel0 = (const float*)d_in[3];
    const float* dq   = (const float*)d_in[4];
    float* yo = (float*)d_out;

    kf_kernel<<<NTRK / 64, 64, 0, stream>>>(zl, lh, pos0, vel0, dq, yo);
}